// Round 12
// baseline (681.284 us; speedup 1.0000x reference)
//
#include <hip/hip_runtime.h>
#include <cstddef>
#include <cmath>

typedef __attribute__((ext_vector_type(8))) short bf16x8;
typedef __attribute__((ext_vector_type(4))) float f32x4;

static __device__ __forceinline__ f32x4 mfma16(bf16x8 a, bf16x8 b, f32x4 c) {
    return __builtin_amdgcn_mfma_f32_16x16x32_bf16(a, b, c, 0, 0, 0);
}
static __device__ __forceinline__ unsigned short f2bf(float f) {
    unsigned int u = __float_as_uint(f);
    return (unsigned short)((u + 0x7FFFu + ((u >> 16) & 1u)) >> 16);
}
static __device__ __forceinline__ bf16x8 asbf(int4 v) {
    union { int4 i; bf16x8 h; } u; u.i = v; return u.h;
}

// ============================ CSR build ============================
// cnt zeroed by hipMemsetAsync. Self-loop is NOT in the CSR list: the edge
// kernel injects it as implicit message 0 (max is idempotent, pad-safe).
__global__ void k_count(const int* __restrict__ ei, int E, unsigned int* __restrict__ cnt) {
    int idx = blockIdx.x * 256 + threadIdx.x;
    int e0 = idx * 4;
    if (e0 + 3 < E) {
        int4 d = ((const int4*)(ei + E))[idx];
        atomicAdd(&cnt[d.x], 1u);
        atomicAdd(&cnt[d.y], 1u);
        atomicAdd(&cnt[d.z], 1u);
        atomicAdd(&cnt[d.w], 1u);
    } else {
        for (int e = e0; e < E; ++e) atomicAdd(&cnt[ei[E + e]], 1u);
    }
}

// exclusive scan; writes off[] and resets cnt[] to cursor start (=off)
__global__ __launch_bounds__(1024) void k_scan(unsigned int* __restrict__ cnt,
                                               unsigned int* __restrict__ off, int N) {
    __shared__ unsigned int sums[1024];
    int t = threadIdx.x;
    int chunk = (N + 1023) >> 10;
    int lo = t * chunk, hi = min(lo + chunk, N);
    unsigned int s = 0;
    for (int i = lo; i < hi; ++i) s += cnt[i];
    sums[t] = s;
    __syncthreads();
    for (int d = 1; d < 1024; d <<= 1) {
        unsigned int v = (t >= d) ? sums[t - d] : 0u;
        __syncthreads();
        sums[t] += v;
        __syncthreads();
    }
    unsigned int run = (t == 0) ? 0u : sums[t - 1];
    for (int i = lo; i < hi; ++i) {
        unsigned int c = cnt[i];
        off[i] = run;
        cnt[i] = run;       // cursor start
        run += c;
    }
}

__global__ void k_scatter(const int* __restrict__ ei, int E,
                          unsigned int* __restrict__ cur, unsigned int* __restrict__ list) {
    int idx = blockIdx.x * 256 + threadIdx.x;
    int e0 = idx * 4;
    if (e0 + 3 < E) {
        int4 s = ((const int4*)ei)[idx];
        int4 d = ((const int4*)(ei + E))[idx];
        unsigned int p0 = atomicAdd(&cur[d.x], 1u);
        unsigned int p1 = atomicAdd(&cur[d.y], 1u);
        unsigned int p2 = atomicAdd(&cur[d.z], 1u);
        unsigned int p3 = atomicAdd(&cur[d.w], 1u);
        list[p0] = (unsigned int)s.x;
        list[p1] = (unsigned int)s.y;
        list[p2] = (unsigned int)s.z;
        list[p3] = (unsigned int)s.w;
    } else {
        for (int e = e0; e < E; ++e) {
            int d = ei[E + e];
            unsigned int p = atomicAdd(&cur[d], 1u);
            list[p] = (unsigned int)ei[e];
        }
    }
}

// ====== weight converter: f32 [K][N] -> bf16 transposed [N][K] (W1 K-padded to 32) ======
__global__ void k_convert(const float* __restrict__ W1, const float* __restrict__ W2,
                          const float* __restrict__ W3, const float* __restrict__ W4,
                          const float* __restrict__ W5,
                          unsigned short* __restrict__ W1bt, unsigned short* __restrict__ W2bt,
                          unsigned short* __restrict__ W3bt, unsigned short* __restrict__ W4bt,
                          unsigned short* __restrict__ W5bt) {
    int id = blockIdx.x * 256 + threadIdx.x;
    if (id < 2048) {                               // W1: [6][64] -> [64][32] zero-padded
        int n = id >> 5, k = id & 31;
        W1bt[id] = (k < 6) ? f2bf(W1[k * 64 + n]) : (unsigned short)0;
    } else if (id < 2048 + 4096) {                 // W2: [64][64] -> [64][64]
        int t = id - 2048;
        int n = t >> 6, k = t & 63;
        W2bt[t] = f2bf(W2[k * 64 + n]);
    } else if (id < 6144 + 8192) {                 // W3: [64][128] -> [128][64]
        int t = id - 6144;
        int n = t >> 6, k = t & 63;
        W3bt[t] = f2bf(W3[k * 128 + n]);
    } else if (id < 14336 + 131072) {              // W4: [128][1024] -> [1024][128]
        int t = id - 14336;
        int n = t >> 7, k = t & 127;
        W4bt[t] = f2bf(W4[k * 1024 + n]);
    } else if (id < 145408 + 65536) {              // W5: [1024][64] -> [64][1024]
        int t = id - 145408;
        int n = t >> 10, k = t & 1023;
        W5bt[t] = f2bf(W5[k * 64 + n]);
    }
}

// ===================== edge kernel: MFMA, one wave per dst, 16 msgs/tile =====================
// Message 0 = implicit self-loop (src=dst, pos diff 0); messages 1..ecnt from CSR list.
// Tile padding duplicates the last message (max idempotent). h C->A round-trip via
// wave-private LDS patch (no barriers).
#define TPB_E 256
#define EDGE_WPB 4
__global__ __launch_bounds__(TPB_E, 3) void edge_kernel(
    const float* __restrict__ x, const float* __restrict__ pos,
    const unsigned int* __restrict__ off, const unsigned int* __restrict__ cur,
    const unsigned int* __restrict__ list,
    const unsigned short* __restrict__ W1bt, const float* __restrict__ b1,
    const unsigned short* __restrict__ W2bt, const float* __restrict__ b2,
    float* __restrict__ agg, int N, int dstStride)
{
    __shared__ __align__(16) short Hs[4][16 * 72];

    int tid = threadIdx.x;
    int lane = tid & 63;
    int w = tid >> 6;
    int lm = lane & 15;
    int quad = lane >> 4;
    short* H = Hs[w];
    int dst0 = blockIdx.x * EDGE_WPB + w;

    bf16x8 B1f[4], B2f[4][2];
    float b1c[4], b2c[4];
#pragma unroll
    for (int nt = 0; nt < 4; ++nt) {
        B1f[nt] = *(const bf16x8*)&W1bt[(nt * 16 + lm) * 32 + quad * 8];
        B2f[nt][0] = *(const bf16x8*)&W2bt[(nt * 16 + lm) * 64 + quad * 8];
        B2f[nt][1] = *(const bf16x8*)&W2bt[(nt * 16 + lm) * 64 + 32 + quad * 8];
        b1c[nt] = b1[nt * 16 + lm];
        b2c[nt] = b2[nt * 16 + lm];
    }

    for (int dst = dst0; dst < N; dst += dstStride) {
        unsigned int o0 = off[dst];
        int ecnt = (int)(cur[dst] - o0);
        int M = ecnt + 1;                    // + implicit self message
        float pi0 = pos[dst * 3 + 0], pi1 = pos[dst * 3 + 1], pi2 = pos[dst * 3 + 2];

        float m0 = -INFINITY, m1 = -INFINITY, m2 = -INFINITY, m3 = -INFINITY;

        for (int base = 0; base < M; base += 16) {
            bf16x8 A = {0, 0, 0, 0, 0, 0, 0, 0};
            if (quad == 0) {
                int i = min(base + lm, M - 1);        // pad = dup last
                int s = (i == 0) ? dst : (int)list[o0 + i - 1];
                A[0] = (short)f2bf(x[s * 3 + 0]);
                A[1] = (short)f2bf(x[s * 3 + 1]);
                A[2] = (short)f2bf(x[s * 3 + 2]);
                A[3] = (short)f2bf(pos[s * 3 + 0] - pi0);
                A[4] = (short)f2bf(pos[s * 3 + 1] - pi1);
                A[5] = (short)f2bf(pos[s * 3 + 2] - pi2);
            }
            // L1: h = relu(A @ W1 + b1)
#pragma unroll
            for (int nt = 0; nt < 4; ++nt) {
                f32x4 c = {0.f, 0.f, 0.f, 0.f};
                c = mfma16(A, B1f[nt], c);
#pragma unroll
                for (int r = 0; r < 4; ++r) {
                    float v = fmaxf(c[r] + b1c[nt], 0.f);
                    H[(quad * 4 + r) * 72 + nt * 16 + lm] = (short)f2bf(v);
                }
            }
            bf16x8 A2a = *(const bf16x8*)&H[lm * 72 + quad * 8];
            bf16x8 A2b = *(const bf16x8*)&H[lm * 72 + 32 + quad * 8];
            // L2 + per-lane row max
            {
                f32x4 c = {0.f, 0.f, 0.f, 0.f};
                c = mfma16(A2a, B2f[0][0], c); c = mfma16(A2b, B2f[0][1], c);
                m0 = fmaxf(m0, fmaxf(fmaxf(c[0], c[1]), fmaxf(c[2], c[3])));
            }
            {
                f32x4 c = {0.f, 0.f, 0.f, 0.f};
                c = mfma16(A2a, B2f[1][0], c); c = mfma16(A2b, B2f[1][1], c);
                m1 = fmaxf(m1, fmaxf(fmaxf(c[0], c[1]), fmaxf(c[2], c[3])));
            }
            {
                f32x4 c = {0.f, 0.f, 0.f, 0.f};
                c = mfma16(A2a, B2f[2][0], c); c = mfma16(A2b, B2f[2][1], c);
                m2 = fmaxf(m2, fmaxf(fmaxf(c[0], c[1]), fmaxf(c[2], c[3])));
            }
            {
                f32x4 c = {0.f, 0.f, 0.f, 0.f};
                c = mfma16(A2a, B2f[3][0], c); c = mfma16(A2b, B2f[3][1], c);
                m3 = fmaxf(m3, fmaxf(fmaxf(c[0], c[1]), fmaxf(c[2], c[3])));
            }
        }

        m0 = fmaxf(m0, __shfl_xor(m0, 16, 64)); m0 = fmaxf(m0, __shfl_xor(m0, 32, 64));
        m1 = fmaxf(m1, __shfl_xor(m1, 16, 64)); m1 = fmaxf(m1, __shfl_xor(m1, 32, 64));
        m2 = fmaxf(m2, __shfl_xor(m2, 16, 64)); m2 = fmaxf(m2, __shfl_xor(m2, 32, 64));
        m3 = fmaxf(m3, __shfl_xor(m3, 16, 64)); m3 = fmaxf(m3, __shfl_xor(m3, 32, 64));

        float mv = (quad == 0) ? m0 : (quad == 1) ? m1 : (quad == 2) ? m2 : m3;
        agg[(size_t)dst * 64 + lane] = mv + b2c[quad];
    }
}

// ===================== node kernel: bf16 MFMA GEMM chain, 64 nodes/block =====================
// R11 lesson: VGPR_Count=48 proved the compiler sank the "batched" weight loads
// back to their uses -> 24 serialized L2 round-trips per chunk. Fix: load all 24
// chunk weights as int4, then asm volatile("" ::: "memory") — loads are memory ops
// and cannot sink past the fence, so they issue as one overlapped cluster
// (one latency exposure per chunk). Expect VGPR ~150.
#define NNODE 64
__global__ __launch_bounds__(256, 2) void node_kernel(
    const float* __restrict__ agg,
    const unsigned short* __restrict__ W3bt, const float* __restrict__ b3,
    const unsigned short* __restrict__ W4bt, const float* __restrict__ b4,
    const unsigned short* __restrict__ W5bt, const float* __restrict__ b5,
    const float* __restrict__ Wf, const float* __restrict__ bf,
    float* __restrict__ out, int N)
{
    __shared__ __align__(16) char smem[17408 + 10496];
    short* G1s = (short*)smem;
    float* G3f = (float*)smem;
    short* G2s = (short*)(smem + 17408);
    float* os  = (float*)(smem + 17408);

    int tid = threadIdx.x;
    int lane = tid & 63;
    int wm = tid >> 6;
    int lm = lane & 15;
    int quad = lane >> 4;
    int n0 = blockIdx.x * NNODE;

    // ---- L3: g1[64x128] = relu(agg @ W3 + b3), K=64 ----
    {
        int arow = min(n0 + wm * 16 + lm, N - 1);
        bf16x8 A3[2];
#pragma unroll
        for (int f = 0; f < 2; ++f) {
            const float* p = agg + (size_t)arow * 64 + f * 32 + quad * 8;
            float4 u = *(const float4*)p;
            float4 v = *(const float4*)(p + 4);
            bf16x8 t;
            t[0] = (short)f2bf(u.x); t[1] = (short)f2bf(u.y);
            t[2] = (short)f2bf(u.z); t[3] = (short)f2bf(u.w);
            t[4] = (short)f2bf(v.x); t[5] = (short)f2bf(v.y);
            t[6] = (short)f2bf(v.z); t[7] = (short)f2bf(v.w);
            A3[f] = t;
        }
#pragma unroll
        for (int nt = 0; nt < 8; ++nt) {
            const unsigned short* wb = W3bt + (nt * 16 + lm) * 64 + quad * 8;
            f32x4 c = {0.f, 0.f, 0.f, 0.f};
            c = mfma16(A3[0], *(const bf16x8*)wb, c);
            c = mfma16(A3[1], *(const bf16x8*)(wb + 32), c);
            float bias = b3[nt * 16 + lm];
#pragma unroll
            for (int r = 0; r < 4; ++r) {
                float v = fmaxf(c[r] + bias, 0.f);
                G1s[(wm * 16 + quad * 4 + r) * 136 + nt * 16 + lm] = (short)f2bf(v);
            }
        }
    }

    bf16x8 A4[4];
#pragma unroll
    for (int f = 0; f < 4; ++f)
        A4[f] = *(const bf16x8*)&G1s[(wm * 16 + lm) * 136 + f * 32 + quad * 8];

    f32x4 acc3[4];
#pragma unroll
    for (int nt = 0; nt < 4; ++nt) {
        float b = b5[nt * 16 + lm];
        acc3[nt][0] = b; acc3[nt][1] = b; acc3[nt][2] = b; acc3[nt][3] = b;
    }

    for (int ch = 0; ch < 16; ++ch) {
        // ---- issue ALL 24 chunk weight loads, then fence so they can't sink ----
        int4 w4r[4][4], w5r[4][2];
#pragma unroll
        for (int nt = 0; nt < 4; ++nt) {
            const unsigned short* wb = W4bt + (size_t)(ch * 64 + nt * 16 + lm) * 128 + quad * 8;
            w4r[nt][0] = *(const int4*)(wb);
            w4r[nt][1] = *(const int4*)(wb + 32);
            w4r[nt][2] = *(const int4*)(wb + 64);
            w4r[nt][3] = *(const int4*)(wb + 96);
        }
#pragma unroll
        for (int nt = 0; nt < 4; ++nt) {
            const unsigned short* wb = W5bt + (size_t)(nt * 16 + lm) * 1024 + ch * 64 + quad * 8;
            w5r[nt][0] = *(const int4*)(wb);
            w5r[nt][1] = *(const int4*)(wb + 32);
        }
        asm volatile("" ::: "memory");   // loads cluster here: one latency exposure

        // L4: g2 chunk = relu(g1 @ W4chunk + b4)
#pragma unroll
        for (int nt = 0; nt < 4; ++nt) {
            f32x4 c = {0.f, 0.f, 0.f, 0.f};
            c = mfma16(A4[0], asbf(w4r[nt][0]), c);
            c = mfma16(A4[1], asbf(w4r[nt][1]), c);
            c = mfma16(A4[2], asbf(w4r[nt][2]), c);
            c = mfma16(A4[3], asbf(w4r[nt][3]), c);
            float bias = b4[ch * 64 + nt * 16 + lm];
#pragma unroll
            for (int r = 0; r < 4; ++r) {
                float v = fmaxf(c[r] + bias, 0.f);
                G2s[(wm * 16 + quad * 4 + r) * 72 + nt * 16 + lm] = (short)f2bf(v);
            }
        }
        // L5: g3 += g2chunk @ W5chunk (C->A via wave-private LDS)
        bf16x8 A5_0 = *(const bf16x8*)&G2s[(wm * 16 + lm) * 72 + quad * 8];
        bf16x8 A5_1 = *(const bf16x8*)&G2s[(wm * 16 + lm) * 72 + 32 + quad * 8];
#pragma unroll
        for (int nt = 0; nt < 4; ++nt) {
            acc3[nt] = mfma16(A5_0, asbf(w5r[nt][0]), acc3[nt]);
            acc3[nt] = mfma16(A5_1, asbf(w5r[nt][1]), acc3[nt]);
        }
    }

#pragma unroll
    for (int nt = 0; nt < 4; ++nt)
#pragma unroll
        for (int r = 0; r < 4; ++r)
            G3f[(wm * 16 + quad * 4 + r) * 68 + nt * 16 + lm] = fmaxf(acc3[nt][r], 0.f);
    __syncthreads();

    for (int idx = tid; idx < NNODE * 40; idx += 256) {
        int ln = idx / 40;
        int c = idx - ln * 40;
        float o = bf[c];
#pragma unroll 4
        for (int j = 0; j < 64; ++j)
            o = fmaf(G3f[ln * 68 + j], Wf[j * 40 + c], o);
        os[ln * 41 + c] = o;
    }
    __syncthreads();

    if (tid < NNODE && n0 + tid < N) {
        int ln = tid;
        float mx = os[ln * 41 + 0];
#pragma unroll
        for (int c = 1; c < 40; ++c) mx = fmaxf(mx, os[ln * 41 + c]);
        float s = 0.f;
#pragma unroll
        for (int c = 0; c < 40; ++c) s += expf(os[ln * 41 + c] - mx);
        float ls = logf(s) + mx;
        float* op = out + (size_t)(n0 + tid) * 40;
#pragma unroll
        for (int c = 0; c < 40; ++c) op[c] = os[ln * 41 + c] - ls;
    }
}

// ============================ launch ============================
extern "C" void kernel_launch(void* const* d_in, const int* in_sizes, int n_in,
                              void* d_out, int out_size, void* d_ws, size_t ws_size,
                              hipStream_t stream) {
    const float* x   = (const float*)d_in[0];
    const float* pos = (const float*)d_in[1];
    const int*   ei  = (const int*)d_in[2];
    const float* W1  = (const float*)d_in[3];
    const float* b1  = (const float*)d_in[4];
    const float* W2  = (const float*)d_in[5];
    const float* b2  = (const float*)d_in[6];
    const float* W3  = (const float*)d_in[7];
    const float* b3  = (const float*)d_in[8];
    const float* W4  = (const float*)d_in[9];
    const float* b4  = (const float*)d_in[10];
    const float* W5  = (const float*)d_in[11];
    const float* b5  = (const float*)d_in[12];
    const float* Wf  = (const float*)d_in[13];
    const float* bf  = (const float*)d_in[14];
    float* out = (float*)d_out;

    int Nn = in_sizes[0] / 3;   // 50000
    int E  = in_sizes[2] / 2;   // 1600000

    char* w = (char*)d_ws;
    size_t p = 0;
    auto take = [&](size_t bytes) { size_t q = p; p = (p + bytes + 255) & ~size_t(255); return (void*)(w + q); };
    unsigned int*   off  = (unsigned int*)take((size_t)Nn * 4);
    unsigned int*   cnt  = (unsigned int*)take((size_t)Nn * 4);   // count -> cursor
    unsigned int*   list = (unsigned int*)take((size_t)E * 4);
    float*          agg  = (float*)take((size_t)Nn * 64 * 4);
    unsigned short* W1bt = (unsigned short*)take(2048 * 2);
    unsigned short* W2bt = (unsigned short*)take(4096 * 2);
    unsigned short* W3bt = (unsigned short*)take(8192 * 2);
    unsigned short* W4bt = (unsigned short*)take(131072 * 2);
    unsigned short* W5bt = (unsigned short*)take(65536 * 2);

    k_convert<<<(2048 + 4096 + 8192 + 131072 + 65536 + 255) / 256, 256, 0, stream>>>(
        W1, W2, W3, W4, W5, W1bt, W2bt, W3bt, W4bt, W5bt);

    hipMemsetAsync(cnt, 0, (size_t)Nn * 4, stream);
    int q4 = (E + 3) / 4;
    k_count<<<(q4 + 255) / 256, 256, 0, stream>>>(ei, E, cnt);
    k_scan<<<1, 1024, 0, stream>>>(cnt, off, Nn);
    k_scatter<<<(q4 + 255) / 256, 256, 0, stream>>>(ei, E, cnt, list);

    int totalWaves = (Nn + 3) / 4;
    int eBlocks = (totalWaves + EDGE_WPB - 1) / EDGE_WPB;
    int dstStride = eBlocks * EDGE_WPB;
    edge_kernel<<<eBlocks, TPB_E, 0, stream>>>(
        x, pos, off, cnt, list, W1bt, b1, W2bt, b2, agg, Nn, dstStride);

    node_kernel<<<(Nn + NNODE - 1) / NNODE, 256, 0, stream>>>(
        agg, W3bt, b3, W4bt, b4, W5bt, b5, Wf, bf, out, Nn);
}

// Round 13
// 636.729 us; speedup vs baseline: 1.0700x; 1.0700x over previous
//
#include <hip/hip_runtime.h>
#include <cstddef>
#include <cmath>

typedef __attribute__((ext_vector_type(8))) short bf16x8;
typedef __attribute__((ext_vector_type(4))) float f32x4;

static __device__ __forceinline__ f32x4 mfma16(bf16x8 a, bf16x8 b, f32x4 c) {
    return __builtin_amdgcn_mfma_f32_16x16x32_bf16(a, b, c, 0, 0, 0);
}
static __device__ __forceinline__ unsigned short f2bf(float f) {
    unsigned int u = __float_as_uint(f);
    return (unsigned short)((u + 0x7FFFu + ((u >> 16) & 1u)) >> 16);
}

// ============================ CSR build ============================
// cnt zeroed by hipMemsetAsync. Self-loop is NOT in the CSR list: the edge
// kernel injects it as implicit message 0 (max is idempotent, pad-safe).
__global__ void k_count(const int* __restrict__ ei, int E, unsigned int* __restrict__ cnt) {
    int idx = blockIdx.x * 256 + threadIdx.x;
    int e0 = idx * 4;
    if (e0 + 3 < E) {
        int4 d = ((const int4*)(ei + E))[idx];
        atomicAdd(&cnt[d.x], 1u);
        atomicAdd(&cnt[d.y], 1u);
        atomicAdd(&cnt[d.z], 1u);
        atomicAdd(&cnt[d.w], 1u);
    } else {
        for (int e = e0; e < E; ++e) atomicAdd(&cnt[ei[E + e]], 1u);
    }
}

// exclusive scan; writes off[] and resets cnt[] to cursor start (=off)
__global__ __launch_bounds__(1024) void k_scan(unsigned int* __restrict__ cnt,
                                               unsigned int* __restrict__ off, int N) {
    __shared__ unsigned int sums[1024];
    int t = threadIdx.x;
    int chunk = (N + 1023) >> 10;
    int lo = t * chunk, hi = min(lo + chunk, N);
    unsigned int s = 0;
    for (int i = lo; i < hi; ++i) s += cnt[i];
    sums[t] = s;
    __syncthreads();
    for (int d = 1; d < 1024; d <<= 1) {
        unsigned int v = (t >= d) ? sums[t - d] : 0u;
        __syncthreads();
        sums[t] += v;
        __syncthreads();
    }
    unsigned int run = (t == 0) ? 0u : sums[t - 1];
    for (int i = lo; i < hi; ++i) {
        unsigned int c = cnt[i];
        off[i] = run;
        cnt[i] = run;       // cursor start
        run += c;
    }
}

__global__ void k_scatter(const int* __restrict__ ei, int E,
                          unsigned int* __restrict__ cur, unsigned int* __restrict__ list) {
    int idx = blockIdx.x * 256 + threadIdx.x;
    int e0 = idx * 4;
    if (e0 + 3 < E) {
        int4 s = ((const int4*)ei)[idx];
        int4 d = ((const int4*)(ei + E))[idx];
        unsigned int p0 = atomicAdd(&cur[d.x], 1u);
        unsigned int p1 = atomicAdd(&cur[d.y], 1u);
        unsigned int p2 = atomicAdd(&cur[d.z], 1u);
        unsigned int p3 = atomicAdd(&cur[d.w], 1u);
        list[p0] = (unsigned int)s.x;
        list[p1] = (unsigned int)s.y;
        list[p2] = (unsigned int)s.z;
        list[p3] = (unsigned int)s.w;
    } else {
        for (int e = e0; e < E; ++e) {
            int d = ei[E + e];
            unsigned int p = atomicAdd(&cur[d], 1u);
            list[p] = (unsigned int)ei[e];
        }
    }
}

// ====== weight converter: f32 [K][N] -> bf16 transposed [N][K] (W1 K-padded to 32) ======
__global__ void k_convert(const float* __restrict__ W1, const float* __restrict__ W2,
                          const float* __restrict__ W3, const float* __restrict__ W4,
                          const float* __restrict__ W5,
                          unsigned short* __restrict__ W1bt, unsigned short* __restrict__ W2bt,
                          unsigned short* __restrict__ W3bt, unsigned short* __restrict__ W4bt,
                          unsigned short* __restrict__ W5bt) {
    int id = blockIdx.x * 256 + threadIdx.x;
    if (id < 2048) {                               // W1: [6][64] -> [64][32] zero-padded
        int n = id >> 5, k = id & 31;
        W1bt[id] = (k < 6) ? f2bf(W1[k * 64 + n]) : (unsigned short)0;
    } else if (id < 2048 + 4096) {                 // W2: [64][64] -> [64][64]
        int t = id - 2048;
        int n = t >> 6, k = t & 63;
        W2bt[t] = f2bf(W2[k * 64 + n]);
    } else if (id < 6144 + 8192) {                 // W3: [64][128] -> [128][64]
        int t = id - 6144;
        int n = t >> 6, k = t & 63;
        W3bt[t] = f2bf(W3[k * 128 + n]);
    } else if (id < 14336 + 131072) {              // W4: [128][1024] -> [1024][128]
        int t = id - 14336;
        int n = t >> 7, k = t & 127;
        W4bt[t] = f2bf(W4[k * 1024 + n]);
    } else if (id < 145408 + 65536) {              // W5: [1024][64] -> [64][1024]
        int t = id - 145408;
        int n = t >> 10, k = t & 1023;
        W5bt[t] = f2bf(W5[k * 64 + n]);
    }
}

// ===================== edge kernel: MFMA, one wave per dst, 16 msgs/tile =====================
#define TPB_E 256
#define EDGE_WPB 4
__global__ __launch_bounds__(TPB_E, 3) void edge_kernel(
    const float* __restrict__ x, const float* __restrict__ pos,
    const unsigned int* __restrict__ off, const unsigned int* __restrict__ cur,
    const unsigned int* __restrict__ list,
    const unsigned short* __restrict__ W1bt, const float* __restrict__ b1,
    const unsigned short* __restrict__ W2bt, const float* __restrict__ b2,
    float* __restrict__ agg, int N, int dstStride)
{
    __shared__ __align__(16) short Hs[4][16 * 72];

    int tid = threadIdx.x;
    int lane = tid & 63;
    int w = tid >> 6;
    int lm = lane & 15;
    int quad = lane >> 4;
    short* H = Hs[w];
    int dst0 = blockIdx.x * EDGE_WPB + w;

    bf16x8 B1f[4], B2f[4][2];
    float b1c[4], b2c[4];
#pragma unroll
    for (int nt = 0; nt < 4; ++nt) {
        B1f[nt] = *(const bf16x8*)&W1bt[(nt * 16 + lm) * 32 + quad * 8];
        B2f[nt][0] = *(const bf16x8*)&W2bt[(nt * 16 + lm) * 64 + quad * 8];
        B2f[nt][1] = *(const bf16x8*)&W2bt[(nt * 16 + lm) * 64 + 32 + quad * 8];
        b1c[nt] = b1[nt * 16 + lm];
        b2c[nt] = b2[nt * 16 + lm];
    }

    for (int dst = dst0; dst < N; dst += dstStride) {
        unsigned int o0 = off[dst];
        int ecnt = (int)(cur[dst] - o0);
        int M = ecnt + 1;                    // + implicit self message
        float pi0 = pos[dst * 3 + 0], pi1 = pos[dst * 3 + 1], pi2 = pos[dst * 3 + 2];

        float m0 = -INFINITY, m1 = -INFINITY, m2 = -INFINITY, m3 = -INFINITY;

        for (int base = 0; base < M; base += 16) {
            bf16x8 A = {0, 0, 0, 0, 0, 0, 0, 0};
            if (quad == 0) {
                int i = min(base + lm, M - 1);        // pad = dup last
                int s = (i == 0) ? dst : (int)list[o0 + i - 1];
                A[0] = (short)f2bf(x[s * 3 + 0]);
                A[1] = (short)f2bf(x[s * 3 + 1]);
                A[2] = (short)f2bf(x[s * 3 + 2]);
                A[3] = (short)f2bf(pos[s * 3 + 0] - pi0);
                A[4] = (short)f2bf(pos[s * 3 + 1] - pi1);
                A[5] = (short)f2bf(pos[s * 3 + 2] - pi2);
            }
            // L1: h = relu(A @ W1 + b1)
#pragma unroll
            for (int nt = 0; nt < 4; ++nt) {
                f32x4 c = {0.f, 0.f, 0.f, 0.f};
                c = mfma16(A, B1f[nt], c);
#pragma unroll
                for (int r = 0; r < 4; ++r) {
                    float v = fmaxf(c[r] + b1c[nt], 0.f);
                    H[(quad * 4 + r) * 72 + nt * 16 + lm] = (short)f2bf(v);
                }
            }
            bf16x8 A2a = *(const bf16x8*)&H[lm * 72 + quad * 8];
            bf16x8 A2b = *(const bf16x8*)&H[lm * 72 + 32 + quad * 8];
            // L2 + per-lane row max
            {
                f32x4 c = {0.f, 0.f, 0.f, 0.f};
                c = mfma16(A2a, B2f[0][0], c); c = mfma16(A2b, B2f[0][1], c);
                m0 = fmaxf(m0, fmaxf(fmaxf(c[0], c[1]), fmaxf(c[2], c[3])));
            }
            {
                f32x4 c = {0.f, 0.f, 0.f, 0.f};
                c = mfma16(A2a, B2f[1][0], c); c = mfma16(A2b, B2f[1][1], c);
                m1 = fmaxf(m1, fmaxf(fmaxf(c[0], c[1]), fmaxf(c[2], c[3])));
            }
            {
                f32x4 c = {0.f, 0.f, 0.f, 0.f};
                c = mfma16(A2a, B2f[2][0], c); c = mfma16(A2b, B2f[2][1], c);
                m2 = fmaxf(m2, fmaxf(fmaxf(c[0], c[1]), fmaxf(c[2], c[3])));
            }
            {
                f32x4 c = {0.f, 0.f, 0.f, 0.f};
                c = mfma16(A2a, B2f[3][0], c); c = mfma16(A2b, B2f[3][1], c);
                m3 = fmaxf(m3, fmaxf(fmaxf(c[0], c[1]), fmaxf(c[2], c[3])));
            }
        }

        m0 = fmaxf(m0, __shfl_xor(m0, 16, 64)); m0 = fmaxf(m0, __shfl_xor(m0, 32, 64));
        m1 = fmaxf(m1, __shfl_xor(m1, 16, 64)); m1 = fmaxf(m1, __shfl_xor(m1, 32, 64));
        m2 = fmaxf(m2, __shfl_xor(m2, 16, 64)); m2 = fmaxf(m2, __shfl_xor(m2, 32, 64));
        m3 = fmaxf(m3, __shfl_xor(m3, 16, 64)); m3 = fmaxf(m3, __shfl_xor(m3, 32, 64));

        float mv = (quad == 0) ? m0 : (quad == 1) ? m1 : (quad == 2) ? m2 : m3;
        agg[(size_t)dst * 64 + lane] = mv + b2c[quad];
    }
}

// ===================== node kernel: 16 nodes / 128-thread block, chunk-split =====================
// R12 lesson: per-wave load-ILP is unobtainable from this compiler (VGPR stayed 48/60
// through batching + asm fences). Buy concurrency with TLP instead: 2-wave blocks,
// wave wv handles chunks [wv*8, wv*8+8) (half the serial latency chain), 6250 waves
// total, ~9 KB LDS, launch_bounds(128,6) -> ~24 resident waves/CU (vs 8.5 before).
#define NNODE 16
__global__ __launch_bounds__(128, 6) void node_kernel(
    const float* __restrict__ agg,
    const unsigned short* __restrict__ W3bt, const float* __restrict__ b3,
    const unsigned short* __restrict__ W4bt, const float* __restrict__ b4,
    const unsigned short* __restrict__ W5bt, const float* __restrict__ b5,
    const float* __restrict__ Wf, const float* __restrict__ bf,
    float* __restrict__ out, int N)
{
    // [0, 4352)    G1s short [16][136]  -> G3f f32 [16][68] (byte-exact overlay)
    // [4352, 8960) G2s short [2][16][72] -> red f32 [16][64] (4096) -> os f32 [16][41]
    __shared__ __align__(16) char smem[8960];
    short* G1s = (short*)smem;
    float* G3f = (float*)smem;
    short* G2s = (short*)(smem + 4352);
    float* red = (float*)(smem + 4352);
    float* os  = (float*)(smem + 4352);

    int tid = threadIdx.x;
    int lane = tid & 63;
    int wv = tid >> 6;            // wave 0/1
    int lm = lane & 15;
    int quad = lane >> 4;
    int n0 = blockIdx.x * NNODE;
    short* G2w = G2s + wv * (16 * 72);

    // ---- L3: g1[16x128] = relu(agg @ W3 + b3); wave wv computes n-tiles wv*4..+4 ----
    {
        int arow = min(n0 + lm, N - 1);
        bf16x8 A3[2];
#pragma unroll
        for (int f = 0; f < 2; ++f) {
            const float* p = agg + (size_t)arow * 64 + f * 32 + quad * 8;
            float4 u = *(const float4*)p;
            float4 v = *(const float4*)(p + 4);
            bf16x8 t;
            t[0] = (short)f2bf(u.x); t[1] = (short)f2bf(u.y);
            t[2] = (short)f2bf(u.z); t[3] = (short)f2bf(u.w);
            t[4] = (short)f2bf(v.x); t[5] = (short)f2bf(v.y);
            t[6] = (short)f2bf(v.z); t[7] = (short)f2bf(v.w);
            A3[f] = t;
        }
#pragma unroll
        for (int t = 0; t < 4; ++t) {
            int nt = wv * 4 + t;
            const unsigned short* wb = W3bt + (nt * 16 + lm) * 64 + quad * 8;
            f32x4 c = {0.f, 0.f, 0.f, 0.f};
            c = mfma16(A3[0], *(const bf16x8*)wb, c);
            c = mfma16(A3[1], *(const bf16x8*)(wb + 32), c);
            float bias = b3[nt * 16 + lm];
#pragma unroll
            for (int r = 0; r < 4; ++r) {
                float v = fmaxf(c[r] + bias, 0.f);
                G1s[(quad * 4 + r) * 136 + nt * 16 + lm] = (short)f2bf(v);
            }
        }
    }
    __syncthreads();

    // ---- A-frags for L4 (same 16 rows for both waves) ----
    bf16x8 A4[4];
#pragma unroll
    for (int f = 0; f < 4; ++f)
        A4[f] = *(const bf16x8*)&G1s[lm * 136 + f * 32 + quad * 8];

    f32x4 acc3[4];
#pragma unroll
    for (int nt = 0; nt < 4; ++nt) {
        float b = (wv == 0) ? b5[nt * 16 + lm] : 0.f;
        acc3[nt][0] = b; acc3[nt][1] = b; acc3[nt][2] = b; acc3[nt][3] = b;
    }

    // ---- L4+L5: wave wv handles chunks [wv*8, wv*8+8) ----
    int ch0 = wv * 8;
    for (int ch = ch0; ch < ch0 + 8; ++ch) {
#pragma unroll
        for (int nt = 0; nt < 4; ++nt) {
            const unsigned short* wb = W4bt + (size_t)(ch * 64 + nt * 16 + lm) * 128 + quad * 8;
            f32x4 c = {0.f, 0.f, 0.f, 0.f};
            c = mfma16(A4[0], *(const bf16x8*)wb, c);
            c = mfma16(A4[1], *(const bf16x8*)(wb + 32), c);
            c = mfma16(A4[2], *(const bf16x8*)(wb + 64), c);
            c = mfma16(A4[3], *(const bf16x8*)(wb + 96), c);
            float bias = b4[ch * 64 + nt * 16 + lm];
#pragma unroll
            for (int r = 0; r < 4; ++r) {
                float v = fmaxf(c[r] + bias, 0.f);
                G2w[(quad * 4 + r) * 72 + nt * 16 + lm] = (short)f2bf(v);
            }
        }
        bf16x8 A5_0 = *(const bf16x8*)&G2w[lm * 72 + quad * 8];
        bf16x8 A5_1 = *(const bf16x8*)&G2w[lm * 72 + 32 + quad * 8];
#pragma unroll
        for (int nt = 0; nt < 4; ++nt) {
            const unsigned short* wb = W5bt + (size_t)(nt * 16 + lm) * 1024 + ch * 64 + quad * 8;
            acc3[nt] = mfma16(A5_0, *(const bf16x8*)wb, acc3[nt]);
            acc3[nt] = mfma16(A5_1, *(const bf16x8*)(wb + 32), acc3[nt]);
        }
    }

    // ---- reduce the 2 chunk-halves: wave1 -> LDS, wave0 adds + relu -> G3f ----
    if (wv == 1) {
#pragma unroll
        for (int nt = 0; nt < 4; ++nt)
#pragma unroll
            for (int r = 0; r < 4; ++r)
                red[(quad * 4 + r) * 64 + nt * 16 + lm] = acc3[nt][r];
    }
    __syncthreads();
    if (wv == 0) {
#pragma unroll
        for (int nt = 0; nt < 4; ++nt)
#pragma unroll
            for (int r = 0; r < 4; ++r) {
                float v = acc3[nt][r] + red[(quad * 4 + r) * 64 + nt * 16 + lm];
                G3f[(quad * 4 + r) * 68 + nt * 16 + lm] = fmaxf(v, 0.f);
            }
    }
    __syncthreads();

    // ---- fc: 16 nodes x 40 outputs (os overlays red/G2s region) ----
    for (int idx = tid; idx < NNODE * 40; idx += 128) {
        int ln = idx / 40;
        int c = idx - ln * 40;
        float o = bf[c];
#pragma unroll 4
        for (int j = 0; j < 64; ++j)
            o = fmaf(G3f[ln * 68 + j], Wf[j * 40 + c], o);
        os[ln * 41 + c] = o;
    }
    __syncthreads();

    // ---- log_softmax + store ----
    if (tid < NNODE && n0 + tid < N) {
        int ln = tid;
        float mx = os[ln * 41 + 0];
#pragma unroll
        for (int c = 1; c < 40; ++c) mx = fmaxf(mx, os[ln * 41 + c]);
        float s = 0.f;
#pragma unroll
        for (int c = 0; c < 40; ++c) s += expf(os[ln * 41 + c] - mx);
        float ls = logf(s) + mx;
        float* op = out + (size_t)(n0 + tid) * 40;
#pragma unroll
        for (int c = 0; c < 40; ++c) op[c] = os[ln * 41 + c] - ls;
    }
}

// ============================ launch ============================
extern "C" void kernel_launch(void* const* d_in, const int* in_sizes, int n_in,
                              void* d_out, int out_size, void* d_ws, size_t ws_size,
                              hipStream_t stream) {
    const float* x   = (const float*)d_in[0];
    const float* pos = (const float*)d_in[1];
    const int*   ei  = (const int*)d_in[2];
    const float* W1  = (const float*)d_in[3];
    const float* b1  = (const float*)d_in[4];
    const float* W2  = (const float*)d_in[5];
    const float* b2  = (const float*)d_in[6];
    const float* W3  = (const float*)d_in[7];
    const float* b3  = (const float*)d_in[8];
    const float* W4  = (const float*)d_in[9];
    const float* b4  = (const float*)d_in[10];
    const float* W5  = (const float*)d_in[11];
    const float* b5  = (const float*)d_in[12];
    const float* Wf  = (const float*)d_in[13];
    const float* bf  = (const float*)d_in[14];
    float* out = (float*)d_out;

    int Nn = in_sizes[0] / 3;   // 50000
    int E  = in_sizes[2] / 2;   // 1600000

    char* w = (char*)d_ws;
    size_t p = 0;
    auto take = [&](size_t bytes) { size_t q = p; p = (p + bytes + 255) & ~size_t(255); return (void*)(w + q); };
    unsigned int*   off  = (unsigned int*)take((size_t)Nn * 4);
    unsigned int*   cnt  = (unsigned int*)take((size_t)Nn * 4);   // count -> cursor
    unsigned int*   list = (unsigned int*)take((size_t)E * 4);
    float*          agg  = (float*)take((size_t)Nn * 64 * 4);
    unsigned short* W1bt = (unsigned short*)take(2048 * 2);
    unsigned short* W2bt = (unsigned short*)take(4096 * 2);
    unsigned short* W3bt = (unsigned short*)take(8192 * 2);
    unsigned short* W4bt = (unsigned short*)take(131072 * 2);
    unsigned short* W5bt = (unsigned short*)take(65536 * 2);

    k_convert<<<(2048 + 4096 + 8192 + 131072 + 65536 + 255) / 256, 256, 0, stream>>>(
        W1, W2, W3, W4, W5, W1bt, W2bt, W3bt, W4bt, W5bt);

    hipMemsetAsync(cnt, 0, (size_t)Nn * 4, stream);
    int q4 = (E + 3) / 4;
    k_count<<<(q4 + 255) / 256, 256, 0, stream>>>(ei, E, cnt);
    k_scan<<<1, 1024, 0, stream>>>(cnt, off, Nn);
    k_scatter<<<(q4 + 255) / 256, 256, 0, stream>>>(ei, E, cnt, list);

    int totalWaves = (Nn + 3) / 4;
    int eBlocks = (totalWaves + EDGE_WPB - 1) / EDGE_WPB;
    int dstStride = eBlocks * EDGE_WPB;
    edge_kernel<<<eBlocks, TPB_E, 0, stream>>>(
        x, pos, off, cnt, list, W1bt, b1, W2bt, b2, agg, Nn, dstStride);

    node_kernel<<<(Nn + NNODE - 1) / NNODE, 128, 0, stream>>>(
        agg, W3bt, b3, W4bt, b4, W5bt, b5, Wf, bf, out, Nn);
}

// Round 14
// 457.476 us; speedup vs baseline: 1.4892x; 1.3918x over previous
//
#include <hip/hip_runtime.h>
#include <cstddef>
#include <cmath>

typedef __attribute__((ext_vector_type(8))) short bf16x8;
typedef __attribute__((ext_vector_type(4))) float f32x4;

static __device__ __forceinline__ f32x4 mfma16(bf16x8 a, bf16x8 b, f32x4 c) {
    return __builtin_amdgcn_mfma_f32_16x16x32_bf16(a, b, c, 0, 0, 0);
}
static __device__ __forceinline__ unsigned short f2bf(float f) {
    unsigned int u = __float_as_uint(f);
    return (unsigned short)((u + 0x7FFFu + ((u >> 16) & 1u)) >> 16);
}

// ============================ CSR build ============================
// cnt zeroed by hipMemsetAsync. Self-loop is injected by the edge kernel as
// implicit message 0 (max is idempotent, pad-safe).
__global__ void k_count(const int* __restrict__ ei, int E, unsigned int* __restrict__ cnt) {
    int idx = blockIdx.x * 256 + threadIdx.x;
    int e0 = idx * 4;
    if (e0 + 3 < E) {
        int4 d = ((const int4*)(ei + E))[idx];
        atomicAdd(&cnt[d.x], 1u);
        atomicAdd(&cnt[d.y], 1u);
        atomicAdd(&cnt[d.z], 1u);
        atomicAdd(&cnt[d.w], 1u);
    } else {
        for (int e = e0; e < E; ++e) atomicAdd(&cnt[ei[E + e]], 1u);
    }
}

// ---- 3-phase multi-block exclusive scan (R13 lesson: 1-block scan serialized the GPU) ----
__global__ __launch_bounds__(256) void k_scan1(const unsigned int* __restrict__ cnt,
                                               unsigned int* __restrict__ part, int N) {
    __shared__ unsigned int red[256];
    int t = threadIdx.x, i = blockIdx.x * 256 + t;
    red[t] = (i < N) ? cnt[i] : 0u;
    __syncthreads();
    for (int d = 128; d > 0; d >>= 1) {
        if (t < d) red[t] += red[t + d];
        __syncthreads();
    }
    if (t == 0) part[blockIdx.x] = red[0];
}

__global__ __launch_bounds__(256) void k_scan2(unsigned int* __restrict__ part, int B) {
    __shared__ unsigned int s[256];
    int t = threadIdx.x;
    s[t] = (t < B) ? part[t] : 0u;
    __syncthreads();
    for (int d = 1; d < 256; d <<= 1) {
        unsigned int v = (t >= d) ? s[t - d] : 0u;
        __syncthreads();
        s[t] += v;
        __syncthreads();
    }
    if (t < B) part[t] = (t == 0) ? 0u : s[t - 1];
}

// writes off[] and resets cnt[] to cursor start (=off)
__global__ __launch_bounds__(256) void k_scan3(unsigned int* __restrict__ cnt,
                                               unsigned int* __restrict__ off,
                                               const unsigned int* __restrict__ part, int N) {
    __shared__ unsigned int s[256];
    int t = threadIdx.x, i = blockIdx.x * 256 + t;
    unsigned int v = (i < N) ? cnt[i] : 0u;
    s[t] = v;
    __syncthreads();
    for (int d = 1; d < 256; d <<= 1) {
        unsigned int u = (t >= d) ? s[t - d] : 0u;
        __syncthreads();
        s[t] += u;
        __syncthreads();
    }
    unsigned int excl = part[blockIdx.x] + s[t] - v;
    if (i < N) { off[i] = excl; cnt[i] = excl; }
}

__global__ void k_scatter(const int* __restrict__ ei, int E,
                          unsigned int* __restrict__ cur, unsigned int* __restrict__ list) {
    int idx = blockIdx.x * 256 + threadIdx.x;
    int e0 = idx * 4;
    if (e0 + 3 < E) {
        int4 s = ((const int4*)ei)[idx];
        int4 d = ((const int4*)(ei + E))[idx];
        unsigned int p0 = atomicAdd(&cur[d.x], 1u);
        unsigned int p1 = atomicAdd(&cur[d.y], 1u);
        unsigned int p2 = atomicAdd(&cur[d.z], 1u);
        unsigned int p3 = atomicAdd(&cur[d.w], 1u);
        list[p0] = (unsigned int)s.x;
        list[p1] = (unsigned int)s.y;
        list[p2] = (unsigned int)s.z;
        list[p3] = (unsigned int)s.w;
    } else {
        for (int e = e0; e < E; ++e) {
            int d = ei[E + e];
            unsigned int p = atomicAdd(&cur[d], 1u);
            list[p] = (unsigned int)ei[e];
        }
    }
}

// ====== weight converter: f32 [K][N] -> bf16 transposed [N][K] ======
// W1 K-padded to 32; W5 laid CHUNK-MAJOR [16][64 n][64 kl] so each 64-k chunk
// is a contiguous 8 KB slab for LDS staging.
__global__ void k_convert(const float* __restrict__ W1, const float* __restrict__ W2,
                          const float* __restrict__ W3, const float* __restrict__ W4,
                          const float* __restrict__ W5,
                          unsigned short* __restrict__ W1bt, unsigned short* __restrict__ W2bt,
                          unsigned short* __restrict__ W3bt, unsigned short* __restrict__ W4bt,
                          unsigned short* __restrict__ W5ct) {
    int id = blockIdx.x * 256 + threadIdx.x;
    if (id < 2048) {                               // W1: [6][64] -> [64][32] zero-padded
        int n = id >> 5, k = id & 31;
        W1bt[id] = (k < 6) ? f2bf(W1[k * 64 + n]) : (unsigned short)0;
    } else if (id < 2048 + 4096) {                 // W2: [64][64] -> [64][64]
        int t = id - 2048;
        int n = t >> 6, k = t & 63;
        W2bt[t] = f2bf(W2[k * 64 + n]);
    } else if (id < 6144 + 8192) {                 // W3: [64][128] -> [128][64]
        int t = id - 6144;
        int n = t >> 6, k = t & 63;
        W3bt[t] = f2bf(W3[k * 128 + n]);
    } else if (id < 14336 + 131072) {              // W4: [128][1024] -> [1024][128]
        int t = id - 14336;
        int n = t >> 7, k = t & 127;
        W4bt[t] = f2bf(W4[k * 1024 + n]);
    } else if (id < 145408 + 65536) {              // W5: [1024][64] -> chunk-major [16][64][64]
        int t = id - 145408;
        int ch = t >> 12, rem = t & 4095;
        int n = rem >> 6, kl = rem & 63;
        W5ct[t] = f2bf(W5[(ch * 64 + kl) * 64 + n]);
    }
}

// ===================== edge kernel: MFMA, one wave per dst, 16 msgs/tile =====================
#define TPB_E 256
#define EDGE_WPB 4
__global__ __launch_bounds__(TPB_E, 3) void edge_kernel(
    const float* __restrict__ x, const float* __restrict__ pos,
    const unsigned int* __restrict__ off, const unsigned int* __restrict__ cur,
    const unsigned int* __restrict__ list,
    const unsigned short* __restrict__ W1bt, const float* __restrict__ b1,
    const unsigned short* __restrict__ W2bt, const float* __restrict__ b2,
    float* __restrict__ agg, int N, int dstStride)
{
    __shared__ __align__(16) short Hs[4][16 * 72];

    int tid = threadIdx.x;
    int lane = tid & 63;
    int w = tid >> 6;
    int lm = lane & 15;
    int quad = lane >> 4;
    short* H = Hs[w];
    int dst0 = blockIdx.x * EDGE_WPB + w;

    bf16x8 B1f[4], B2f[4][2];
    float b1c[4], b2c[4];
#pragma unroll
    for (int nt = 0; nt < 4; ++nt) {
        B1f[nt] = *(const bf16x8*)&W1bt[(nt * 16 + lm) * 32 + quad * 8];
        B2f[nt][0] = *(const bf16x8*)&W2bt[(nt * 16 + lm) * 64 + quad * 8];
        B2f[nt][1] = *(const bf16x8*)&W2bt[(nt * 16 + lm) * 64 + 32 + quad * 8];
        b1c[nt] = b1[nt * 16 + lm];
        b2c[nt] = b2[nt * 16 + lm];
    }

    for (int dst = dst0; dst < N; dst += dstStride) {
        unsigned int o0 = off[dst];
        int ecnt = (int)(cur[dst] - o0);
        int M = ecnt + 1;                    // + implicit self message
        float pi0 = pos[dst * 3 + 0], pi1 = pos[dst * 3 + 1], pi2 = pos[dst * 3 + 2];

        float m0 = -INFINITY, m1 = -INFINITY, m2 = -INFINITY, m3 = -INFINITY;

        for (int base = 0; base < M; base += 16) {
            bf16x8 A = {0, 0, 0, 0, 0, 0, 0, 0};
            if (quad == 0) {
                int i = min(base + lm, M - 1);        // pad = dup last
                int s = (i == 0) ? dst : (int)list[o0 + i - 1];
                A[0] = (short)f2bf(x[s * 3 + 0]);
                A[1] = (short)f2bf(x[s * 3 + 1]);
                A[2] = (short)f2bf(x[s * 3 + 2]);
                A[3] = (short)f2bf(pos[s * 3 + 0] - pi0);
                A[4] = (short)f2bf(pos[s * 3 + 1] - pi1);
                A[5] = (short)f2bf(pos[s * 3 + 2] - pi2);
            }
            // L1: h = relu(A @ W1 + b1)
#pragma unroll
            for (int nt = 0; nt < 4; ++nt) {
                f32x4 c = {0.f, 0.f, 0.f, 0.f};
                c = mfma16(A, B1f[nt], c);
#pragma unroll
                for (int r = 0; r < 4; ++r) {
                    float v = fmaxf(c[r] + b1c[nt], 0.f);
                    H[(quad * 4 + r) * 72 + nt * 16 + lm] = (short)f2bf(v);
                }
            }
            bf16x8 A2a = *(const bf16x8*)&H[lm * 72 + quad * 8];
            bf16x8 A2b = *(const bf16x8*)&H[lm * 72 + 32 + quad * 8];
            // L2 + per-lane row max
            {
                f32x4 c = {0.f, 0.f, 0.f, 0.f};
                c = mfma16(A2a, B2f[0][0], c); c = mfma16(A2b, B2f[0][1], c);
                m0 = fmaxf(m0, fmaxf(fmaxf(c[0], c[1]), fmaxf(c[2], c[3])));
            }
            {
                f32x4 c = {0.f, 0.f, 0.f, 0.f};
                c = mfma16(A2a, B2f[1][0], c); c = mfma16(A2b, B2f[1][1], c);
                m1 = fmaxf(m1, fmaxf(fmaxf(c[0], c[1]), fmaxf(c[2], c[3])));
            }
            {
                f32x4 c = {0.f, 0.f, 0.f, 0.f};
                c = mfma16(A2a, B2f[2][0], c); c = mfma16(A2b, B2f[2][1], c);
                m2 = fmaxf(m2, fmaxf(fmaxf(c[0], c[1]), fmaxf(c[2], c[3])));
            }
            {
                f32x4 c = {0.f, 0.f, 0.f, 0.f};
                c = mfma16(A2a, B2f[3][0], c); c = mfma16(A2b, B2f[3][1], c);
                m3 = fmaxf(m3, fmaxf(fmaxf(c[0], c[1]), fmaxf(c[2], c[3])));
            }
        }

        m0 = fmaxf(m0, __shfl_xor(m0, 16, 64)); m0 = fmaxf(m0, __shfl_xor(m0, 32, 64));
        m1 = fmaxf(m1, __shfl_xor(m1, 16, 64)); m1 = fmaxf(m1, __shfl_xor(m1, 32, 64));
        m2 = fmaxf(m2, __shfl_xor(m2, 16, 64)); m2 = fmaxf(m2, __shfl_xor(m2, 32, 64));
        m3 = fmaxf(m3, __shfl_xor(m3, 16, 64)); m3 = fmaxf(m3, __shfl_xor(m3, 32, 64));

        float mv = (quad == 0) ? m0 : (quad == 1) ? m1 : (quad == 2) ? m2 : m3;
        agg[(size_t)dst * 64 + lane] = mv + b2c[quad];
    }
}

// ===================== node kernel: LDS-staged dbuf weights, 64 nodes/block =====================
// R11-R13 lesson: compiler sinks global loads to MFMA uses -> serial latency chain;
// the ONE structure it can't defeat is global->LDS staging (loads feed ds_writes,
// drained once per chunk at the barrier). 4 waves m-split (wave-private rows, no
// reduction); stage(ch+1) overlaps compute(ch); 1 barrier/chunk. LDS rows padded
// (136/72 shorts) for <=2-way banks. ~78 KB LDS -> 2 blocks/CU.
#define NNODE 64
__global__ __launch_bounds__(256, 2) void node_kernel(
    const float* __restrict__ agg,
    const unsigned short* __restrict__ W3bt, const float* __restrict__ b3,
    const unsigned short* __restrict__ W4bt, const float* __restrict__ b4,
    const unsigned short* __restrict__ W5ct, const float* __restrict__ b5,
    const float* __restrict__ Wf, const float* __restrict__ bf,
    float* __restrict__ out, int N)
{
    // [0,     17408) G1s short [64][136] -> G3f f32 [64][68] (byte-exact overlay)
    // [17408, 26624) G2s short [64][72]  (wave-private rows)
    // [26624, 61440) Wb4 short [2][64][136] -> os f32 [64][41] overlay after loop
    // [61440, 79872) Wb5 short [2][64][72]
    __shared__ __align__(16) char smem[79872];
    short* G1s = (short*)smem;
    float* G3f = (float*)smem;
    short* G2s = (short*)(smem + 17408);
    short* Wb4 = (short*)(smem + 26624);
    short* Wb5 = (short*)(smem + 61440);
    float* os  = (float*)(smem + 26624);

    int tid = threadIdx.x;
    int lane = tid & 63;
    int wm = tid >> 6;
    int lm = lane & 15;
    int quad = lane >> 4;
    int n0 = blockIdx.x * NNODE;

    // cooperative staging of one 64-col chunk: 16 KB W4-slab + 8 KB W5-slab
    auto stage = [&](int ch, int buf) {
        const unsigned short* g4 = W4bt + (size_t)ch * 8192;   // contiguous slab
        short* d4 = Wb4 + buf * 8704;
#pragma unroll
        for (int it = 0; it < 4; ++it) {
            int v = tid + it * 256;                            // b128 vector index
            *(int4*)&d4[(v >> 4) * 136 + (v & 15) * 8] = *(const int4*)(g4 + v * 8);
        }
        const unsigned short* g5 = W5ct + (size_t)ch * 4096;   // contiguous slab
        short* d5 = Wb5 + buf * 4608;
#pragma unroll
        for (int it = 0; it < 2; ++it) {
            int v = tid + it * 256;
            *(int4*)&d5[(v >> 3) * 72 + (v & 7) * 8] = *(const int4*)(g5 + v * 8);
        }
    };

    stage(0, 0);   // issue chunk-0 staging; L3 compute below overlaps its latency

    // ---- L3: g1[64x128] = relu(agg @ W3 + b3); wave wm owns rows wm*16..+16 ----
    {
        int arow = min(n0 + wm * 16 + lm, N - 1);
        bf16x8 A3[2];
#pragma unroll
        for (int f = 0; f < 2; ++f) {
            const float* p = agg + (size_t)arow * 64 + f * 32 + quad * 8;
            float4 u = *(const float4*)p;
            float4 v = *(const float4*)(p + 4);
            bf16x8 t;
            t[0] = (short)f2bf(u.x); t[1] = (short)f2bf(u.y);
            t[2] = (short)f2bf(u.z); t[3] = (short)f2bf(u.w);
            t[4] = (short)f2bf(v.x); t[5] = (short)f2bf(v.y);
            t[6] = (short)f2bf(v.z); t[7] = (short)f2bf(v.w);
            A3[f] = t;
        }
#pragma unroll
        for (int nt = 0; nt < 8; ++nt) {
            const unsigned short* wb = W3bt + (nt * 16 + lm) * 64 + quad * 8;
            f32x4 c = {0.f, 0.f, 0.f, 0.f};
            c = mfma16(A3[0], *(const bf16x8*)wb, c);
            c = mfma16(A3[1], *(const bf16x8*)(wb + 32), c);
            float bias = b3[nt * 16 + lm];
#pragma unroll
            for (int r = 0; r < 4; ++r) {
                float v = fmaxf(c[r] + bias, 0.f);
                G1s[(wm * 16 + quad * 4 + r) * 136 + nt * 16 + lm] = (short)f2bf(v);
            }
        }
    }

    // A-frags for L4 (own rows; same-wave LDS, compiler handles lgkmcnt)
    bf16x8 A4[4];
#pragma unroll
    for (int f = 0; f < 4; ++f)
        A4[f] = *(const bf16x8*)&G1s[(wm * 16 + lm) * 136 + f * 32 + quad * 8];

    f32x4 acc3[4];
#pragma unroll
    for (int nt = 0; nt < 4; ++nt) {
        float b = b5[nt * 16 + lm];
        acc3[nt][0] = b; acc3[nt][1] = b; acc3[nt][2] = b; acc3[nt][3] = b;
    }

    __syncthreads();   // chunk-0 staging visible

    // ---- L4+L5 over 16 chunks; stage(ch+1) overlaps compute(ch); 1 barrier/chunk ----
    for (int ch = 0; ch < 16; ++ch) {
        int buf = ch & 1;
        if (ch < 15) stage(ch + 1, buf ^ 1);

        const short* w4b = Wb4 + buf * 8704;
        const short* w5b = Wb5 + buf * 4608;

        // L4: g2 chunk = relu(g1 @ W4chunk + b4), weights from LDS
#pragma unroll
        for (int nt = 0; nt < 4; ++nt) {
            const short* wb = w4b + (nt * 16 + lm) * 136 + quad * 8;
            f32x4 c = {0.f, 0.f, 0.f, 0.f};
            c = mfma16(A4[0], *(const bf16x8*)wb, c);
            c = mfma16(A4[1], *(const bf16x8*)(wb + 32), c);
            c = mfma16(A4[2], *(const bf16x8*)(wb + 64), c);
            c = mfma16(A4[3], *(const bf16x8*)(wb + 96), c);
            float bias = b4[ch * 64 + nt * 16 + lm];
#pragma unroll
            for (int r = 0; r < 4; ++r) {
                float v = fmaxf(c[r] + bias, 0.f);
                G2s[(wm * 16 + quad * 4 + r) * 72 + nt * 16 + lm] = (short)f2bf(v);
            }
        }
        // L5: g3 += g2chunk @ W5chunk (A via wave-private LDS, B from LDS)
        bf16x8 A5_0 = *(const bf16x8*)&G2s[(wm * 16 + lm) * 72 + quad * 8];
        bf16x8 A5_1 = *(const bf16x8*)&G2s[(wm * 16 + lm) * 72 + 32 + quad * 8];
#pragma unroll
        for (int nt = 0; nt < 4; ++nt) {
            const short* wb = w5b + (nt * 16 + lm) * 72 + quad * 8;
            acc3[nt] = mfma16(A5_0, *(const bf16x8*)wb, acc3[nt]);
            acc3[nt] = mfma16(A5_1, *(const bf16x8*)(wb + 32), acc3[nt]);
        }
        __syncthreads();   // staging(ch+1) done + all reads of buf done
    }

    // ---- stage relu(g3): G3f overlays G1s (wave-private rows) ----
#pragma unroll
    for (int nt = 0; nt < 4; ++nt)
#pragma unroll
        for (int r = 0; r < 4; ++r)
            G3f[(wm * 16 + quad * 4 + r) * 68 + nt * 16 + lm] = fmaxf(acc3[nt][r], 0.f);
    __syncthreads();

    // ---- fc: 64 nodes x 40 outputs (os overlays dead Wb4) ----
    for (int idx = tid; idx < NNODE * 40; idx += 256) {
        int ln = idx / 40;
        int c = idx - ln * 40;
        float o = bf[c];
#pragma unroll 4
        for (int j = 0; j < 64; ++j)
            o = fmaf(G3f[ln * 68 + j], Wf[j * 40 + c], o);
        os[ln * 41 + c] = o;
    }
    __syncthreads();

    // ---- log_softmax + store ----
    if (tid < NNODE && n0 + tid < N) {
        int ln = tid;
        float mx = os[ln * 41 + 0];
#pragma unroll
        for (int c = 1; c < 40; ++c) mx = fmaxf(mx, os[ln * 41 + c]);
        float s = 0.f;
#pragma unroll
        for (int c = 0; c < 40; ++c) s += expf(os[ln * 41 + c] - mx);
        float ls = logf(s) + mx;
        float* op = out + (size_t)(n0 + tid) * 40;
#pragma unroll
        for (int c = 0; c < 40; ++c) op[c] = os[ln * 41 + c] - ls;
    }
}

// ============================ launch ============================
extern "C" void kernel_launch(void* const* d_in, const int* in_sizes, int n_in,
                              void* d_out, int out_size, void* d_ws, size_t ws_size,
                              hipStream_t stream) {
    const float* x   = (const float*)d_in[0];
    const float* pos = (const float*)d_in[1];
    const int*   ei  = (const int*)d_in[2];
    const float* W1  = (const float*)d_in[3];
    const float* b1  = (const float*)d_in[4];
    const float* W2  = (const float*)d_in[5];
    const float* b2  = (const float*)d_in[6];
    const float* W3  = (const float*)d_in[7];
    const float* b3  = (const float*)d_in[8];
    const float* W4  = (const float*)d_in[9];
    const float* b4  = (const float*)d_in[10];
    const float* W5  = (const float*)d_in[11];
    const float* b5  = (const float*)d_in[12];
    const float* Wf  = (const float*)d_in[13];
    const float* bf  = (const float*)d_in[14];
    float* out = (float*)d_out;

    int Nn = in_sizes[0] / 3;   // 50000
    int E  = in_sizes[2] / 2;   // 1600000

    char* w = (char*)d_ws;
    size_t p = 0;
    auto take = [&](size_t bytes) { size_t q = p; p = (p + bytes + 255) & ~size_t(255); return (void*)(w + q); };
    unsigned int*   off  = (unsigned int*)take((size_t)Nn * 4);
    unsigned int*   cnt  = (unsigned int*)take((size_t)Nn * 4);   // count -> cursor
    unsigned int*   part = (unsigned int*)take(256 * 4);
    unsigned int*   list = (unsigned int*)take((size_t)E * 4);
    float*          agg  = (float*)take((size_t)Nn * 64 * 4);
    unsigned short* W1bt = (unsigned short*)take(2048 * 2);
    unsigned short* W2bt = (unsigned short*)take(4096 * 2);
    unsigned short* W3bt = (unsigned short*)take(8192 * 2);
    unsigned short* W4bt = (unsigned short*)take(131072 * 2);
    unsigned short* W5ct = (unsigned short*)take(65536 * 2);

    k_convert<<<(2048 + 4096 + 8192 + 131072 + 65536 + 255) / 256, 256, 0, stream>>>(
        W1, W2, W3, W4, W5, W1bt, W2bt, W3bt, W4bt, W5ct);

    hipMemsetAsync(cnt, 0, (size_t)Nn * 4, stream);
    int q4 = (E + 3) / 4;
    k_count<<<(q4 + 255) / 256, 256, 0, stream>>>(ei, E, cnt);
    int sb = (Nn + 255) / 256;                    // 196 scan blocks
    k_scan1<<<sb, 256, 0, stream>>>(cnt, part, Nn);
    k_scan2<<<1, 256, 0, stream>>>(part, sb);
    k_scan3<<<sb, 256, 0, stream>>>(cnt, off, part, Nn);
    k_scatter<<<(q4 + 255) / 256, 256, 0, stream>>>(ei, E, cnt, list);

    int totalWaves = (Nn + 3) / 4;
    int eBlocks = (totalWaves + EDGE_WPB - 1) / EDGE_WPB;
    int dstStride = eBlocks * EDGE_WPB;
    edge_kernel<<<eBlocks, TPB_E, 0, stream>>>(
        x, pos, off, cnt, list, W1bt, b1, W2bt, b2, agg, Nn, dstStride);

    node_kernel<<<(Nn + NNODE - 1) / NNODE, 256, 0, stream>>>(
        agg, W3bt, b3, W4bt, b4, W5ct, b5, Wf, bf, out, Nn);
}